// Round 6
// baseline (719.441 us; speedup 1.0000x reference)
//
#include <hip/hip_runtime.h>
#include <stdint.h>

#define B_ROWS 32768
#define F_DIM  1024
#define H_DIM  512

typedef __attribute__((ext_vector_type(4))) float    floatx4;
typedef __attribute__((ext_vector_type(2))) __fp16   fp16x2;
typedef __attribute__((ext_vector_type(8))) _Float16 halfx8;

__device__ __forceinline__ void async_load16(const void* g, void* l) {
    __builtin_amdgcn_global_load_lds(
        (const __attribute__((address_space(1))) void*)g,
        (__attribute__((address_space(3))) void*)l, 16, 0, 0);
}

// Non-temporal 16B load: keeps the 512MB w stream out of L2 (R5: -36%).
__device__ __forceinline__ floatx4 nt_load4(const float* p) {
    return __builtin_nontemporal_load((const floatx4*)p);
}

// --------------------------------------------------------------------------
// Wcomb[k,d,f] = sum_h Wqkv[k,d,h] * Wlin[k,h,f]   (d: 0-9 q, 10-19 k, 20-29 v)
// bcomb[k,d]   = b[k,d] + sum_h Wqkv[k,d,h] * blin[k,h]
// (unchanged from R5)
// --------------------------------------------------------------------------
__global__ __launch_bounds__(128) void k_prep(
    const float* __restrict__ Wlin, const float* __restrict__ blin,
    const float* __restrict__ Wq, const float* __restrict__ Wk,
    const float* __restrict__ Wv, const float* __restrict__ bq,
    const float* __restrict__ bk, const float* __restrict__ bv,
    ushort* __restrict__ Wcomb16, float* __restrict__ bcomb)
{
    __shared__ float sw_[H_DIM];
    __shared__ float sbl[H_DIM];
    const int bx   = blockIdx.x;
    const int k    = bx >> 6;
    const int d    = (bx >> 1) & 31;
    const int half = bx & 1;
    const int t    = threadIdx.x;
    const int col  = half * 512 + t * 4;
    ushort4* outp = (ushort4*)(Wcomb16 + (((size_t)(k * 32 + d)) << 10) + col);

    if (d >= 30) {
        ushort4 z; z.x = z.y = z.z = z.w = 0;
        *outp = z;
        if (half == 0 && t == 0) bcomb[k * 32 + d] = 0.f;
        return;
    }

    const float* wrow; float bias;
    if (d < 10)      { wrow = Wq + (size_t)(k * 10 + d) * H_DIM;      bias = bq[k * 10 + d]; }
    else if (d < 20) { wrow = Wk + (size_t)(k * 10 + d - 10) * H_DIM; bias = bk[k * 10 + d - 10]; }
    else             { wrow = Wv + (size_t)(k * 10 + d - 20) * H_DIM; bias = bv[k * 10 + d - 20]; }

    const float* bl = blin + (size_t)k * H_DIM;
    for (int i = t; i < H_DIM; i += 128) { sw_[i] = wrow[i]; sbl[i] = bl[i]; }
    __syncthreads();

    const float* wl = Wlin + (((size_t)k * H_DIM) << 10) + col;

    floatx4 acc0 = {0.f,0.f,0.f,0.f}, acc1 = {0.f,0.f,0.f,0.f};
    float ba0 = 0.f, ba1 = 0.f;
    #pragma unroll 8
    for (int h = 0; h < H_DIM; h += 2) {
        const float s0 = sw_[h], s1 = sw_[h + 1];
        const floatx4 x0 = *(const floatx4*)(wl + ((size_t)h << 10));
        const floatx4 x1 = *(const floatx4*)(wl + ((size_t)(h + 1) << 10));
        acc0 += x0 * s0;
        acc1 += x1 * s1;
        ba0 += s0 * sbl[h];
        ba1 += s1 * sbl[h + 1];
    }
    const floatx4 acc = acc0 + acc1;
    union { _Float16 h[4]; ushort4 u; } o;
    o.h[0] = (_Float16)acc.x; o.h[1] = (_Float16)acc.y;
    o.h[2] = (_Float16)acc.z; o.h[3] = (_Float16)acc.w;
    *outp = o.u;
    if (half == 0 && t == 0) bcomb[k * 32 + d] = bias + ba0 + ba1;
}

// --------------------------------------------------------------------------
// FUSED qkv+attention. v3 main loop: one fully-unrolled 128-step stream
// (4 heads x 32 K-steps):
//  - 8-deep A prefetch (16 nt-loads in flight/wave; imm-offset folded)
//  - Bs(k+1) register-staged (T14): global->reg issued at head-k start,
//    ds_write at the boundary -> HBM latency hidden under compute
//  - boundaries use raw s_barrier + lgkmcnt(0) only: vmcnt NEVER drains
//    after the initial stage, so the A stream stays in flight end-to-end.
// Safety: Bs reads are consumed by MFMAs before barrier-1 (so overwrite
// after it is safe); ds_writes complete before barrier-2 via lgkmcnt(0)
// (+ sched_barrier per rule #18).
// --------------------------------------------------------------------------
#define SM_BS    0                        // 64 KiB  ushort[32*1024]
#define SM_QKV   (64 * 1024)              // 61.9 KiB float[128*121]
#define SM_BC    (SM_QKV + 128 * 121 * 4) // 512 B   float[128]
#define SM_W     (SM_BC + 512)            // 1600 B  float[400]
#define SM_B     (SM_W + 1600)            // 160 B   float[40]
#define SM_TOTAL (SM_B + 160)             // 129,824 B

__global__ __launch_bounds__(512, 2) void k_all(
    const float* __restrict__ w0, const float* __restrict__ w1,
    const float* __restrict__ w2, const float* __restrict__ w3,
    const ushort* __restrict__ Wcomb16, const float* __restrict__ bcomb,
    const float* __restrict__ Wfin, const float* __restrict__ bfin,
    float* __restrict__ outputs, float* __restrict__ attn)
{
    __shared__ __align__(16) unsigned char smem[SM_TOTAL];
    ushort* Bs  = (ushort*)(smem + SM_BS);
    float*  QKV = (float*) (smem + SM_QKV);   // [128][121]
    float*  sbc = (float*) (smem + SM_BC);
    float*  sW  = (float*) (smem + SM_W);
    float*  sb  = (float*) (smem + SM_B);
    float*  sA  = (float*) (smem + SM_BS);    // overlay after heads: [128][101]

    const int tid     = threadIdx.x;
    const int rowBase = blockIdx.x * 128;

    if (tid < 128) sbc[tid] = bcomb[tid];
    if (tid < 400) sW[tid]  = Wfin[tid];
    if (tid < 40)  sb[tid]  = bfin[tid];

    const int wv = tid >> 6;          // 0..7
    const int ln = tid & 63;
    const int lr = ln & 15;
    const int lq = ln >> 4;
    const int sw = lr & 7;            // Bs read-side swizzle key

    // ---- initial Bs (head 0): async global->LDS, slot-swizzled source
    #pragma unroll
    for (int it = 0; it < 8; ++it) {
        const int s   = it * 512 + tid;
        const int row = s >> 7;
        const int g   = (s & 127) ^ (row & 7);
        async_load16(Wcomb16 + (((size_t)row) << 10) + g * 8,
                     (ushort*)Bs + (size_t)s * 8);
    }
    __syncthreads();                  // the ONLY vmcnt(0) drain in the kernel

    const size_t aoff = (size_t)(rowBase + wv * 16 + lr) * F_DIM + lq * 8;
    const float* aPk[4] = { w0 + aoff, w1 + aoff, w2 + aoff, w3 + aoff };

    floatx4 abuf[16];                 // 8-deep x 2; all indices static
    #pragma unroll
    for (int s = 0; s < 8; ++s) {
        abuf[(s & 7) * 2]     = nt_load4(aPk[0] + s * 32);
        abuf[(s & 7) * 2 + 1] = nt_load4(aPk[0] + s * 32 + 4);
    }

    uint4 breg[8];                    // next head's Bs share (128 B/thread)
    floatx4 acc0 = {0.f,0.f,0.f,0.f};
    floatx4 acc1 = {0.f,0.f,0.f,0.f};

    #pragma unroll
    for (int s = 0; s < 128; ++s) {
        const int k = s >> 5;
        const int t = s & 31;

        if (t == 0 && s > 0) {
            __builtin_amdgcn_s_barrier();     // raw: all Bs(k-1) reads consumed
            #pragma unroll
            for (int it = 0; it < 8; ++it)
                *(uint4*)((ushort*)Bs + (size_t)(it * 512 + tid) * 8) = breg[it];
            asm volatile("s_waitcnt lgkmcnt(0)" ::: "memory");
            __builtin_amdgcn_sched_barrier(0);
            __builtin_amdgcn_s_barrier();     // Bs(k) visible; vmcnt untouched
            acc0 = (floatx4){0.f,0.f,0.f,0.f};
            acc1 = (floatx4){0.f,0.f,0.f,0.f};
        }

        if (t == 1 && k < 3) {                // stage Bs(k+1) into registers
            #pragma unroll
            for (int it = 0; it < 8; ++it) {
                const int sl  = it * 512 + tid;
                const int row = sl >> 7;
                const int g   = (sl & 127) ^ (row & 7);
                breg[it] = *(const uint4*)(Wcomb16 +
                              (((size_t)((k + 1) * 32 + row)) << 10) + g * 8);
            }
        }

        // ---- compute step t (head k) from abuf slot s&7
        {
            const floatx4 b0 = abuf[(s & 7) * 2];
            const floatx4 b1 = abuf[(s & 7) * 2 + 1];
            union { fp16x2 h2[4]; halfx8 h8; } u;
            u.h2[0] = __builtin_amdgcn_cvt_pkrtz(b0.x, b0.y);
            u.h2[1] = __builtin_amdgcn_cvt_pkrtz(b0.z, b0.w);
            u.h2[2] = __builtin_amdgcn_cvt_pkrtz(b1.x, b1.y);
            u.h2[3] = __builtin_amdgcn_cvt_pkrtz(b1.z, b1.w);
            const int slot_ = ((t * 4 + lq) ^ sw) * 8;
            const halfx8 bf0 = *(const halfx8*)&Bs[(lr << 10) + slot_];
            const halfx8 bf1 = *(const halfx8*)&Bs[((16 + lr) << 10) + slot_];
            acc0 = __builtin_amdgcn_mfma_f32_16x16x32_f16(u.h8, bf0, acc0, 0, 0, 0);
            acc1 = __builtin_amdgcn_mfma_f32_16x16x32_f16(u.h8, bf1, acc1, 0, 0, 0);
        }

        // ---- refill slot with step s+8 (crosses head boundaries)
        if (s + 8 < 128) {
            const int kn = (s + 8) >> 5;
            const int tn = (s + 8) & 31;
            abuf[(s & 7) * 2]     = nt_load4(aPk[kn] + tn * 32);
            abuf[(s & 7) * 2 + 1] = nt_load4(aPk[kn] + tn * 32 + 4);
        }

        if (t == 31) {                        // QKV writes for head k
            const int r0 = wv * 16 + lq * 4;
            #pragma unroll
            for (int r = 0; r < 4; ++r)
                QKV[(r0 + r) * 121 + k * 30 + lr] = acc0[r] + sbc[k * 32 + lr];
            const int d1 = 16 + lr;
            if (d1 < ((k == 0) ? 30 : 20)) {  // v only needed for head 0
                #pragma unroll
                for (int r = 0; r < 4; ++r)
                    QKV[(r0 + r) * 121 + k * 30 + d1] = acc1[r] + sbc[k * 32 + d1];
            }
        }
    }
    __syncthreads();   // QKV complete; Bs dead from here (sA overlays it)

    // ---------------- attention + heads epilogue (threads 0-127, 1 b-row each)
    float oc[10];
    if (tid < 128) {
        const float* Q = &QKV[tid * 121];
        float q[4][10], kk[4][10], v0[10];
        #pragma unroll
        for (int k = 0; k < 4; ++k)
            #pragma unroll
            for (int e = 0; e < 10; ++e) {
                q[k][e]  = Q[k * 30 + e];
                kk[k][e] = Q[k * 30 + 10 + e];
            }
        #pragma unroll
        for (int m = 0; m < 10; ++m) v0[m] = Q[20 + m];   // v, head 0

        float out0[10];
        #pragma unroll
        for (int e = 0; e < 10; ++e) out0[e] = 0.f;
        float* sAr = &sA[tid * 101];
        const float inv = 0.31622776601683794f;  // 1/sqrt(10)

        #pragma unroll
        for (int m = 0; m < 10; ++m) {
            float col[10]; float mx = -1e30f;
            #pragma unroll
            for (int e = 0; e < 10; ++e) {
                col[e] = (q[0][e]*kk[0][m] + q[1][e]*kk[1][m]
                        + q[2][e]*kk[2][m] + q[3][e]*kk[3][m]) * inv;
                mx = fmaxf(mx, col[e]);
            }
            float s = 0.f;
            #pragma unroll
            for (int e = 0; e < 10; ++e) { col[e] = __expf(col[e] - mx); s += col[e]; }
            const float r = 1.f / s;
            #pragma unroll
            for (int e = 0; e < 10; ++e) {
                const float a = col[e] * r;
                sAr[e * 10 + m] = a;
                out0[e] += a * v0[m];
            }
        }

        #pragma unroll
        for (int c = 0; c < 10; ++c) oc[c] = 0.f;
        #pragma unroll
        for (int k = 0; k < 4; ++k) {
            float lg[10]; float mx = -1e30f;
            #pragma unroll
            for (int c = 0; c < 10; ++c) {
                float s = sb[k * 10 + c];
                #pragma unroll
                for (int e = 0; e < 10; ++e) s += out0[e] * sW[(k * 10 + c) * 10 + e];
                lg[c] = s; mx = fmaxf(mx, s);
            }
            float s = 0.f;
            #pragma unroll
            for (int c = 0; c < 10; ++c) { lg[c] = __expf(lg[c] - mx); s += lg[c]; }
            const float r = 0.25f / s;
            #pragma unroll
            for (int c = 0; c < 10; ++c) oc[c] += lg[c] * r;
        }
    }

    // ---- coalesced attn writeback: 128 b x 100 = 12800 floats
    __syncthreads();
    const size_t abase = (size_t)blockIdx.x * 12800;
    for (int i = tid; i < 12800; i += 512) {
        const int bl = i / 100;
        attn[abase + i] = sA[bl * 101 + (i - bl * 100)];
    }

    // ---- coalesced outputs writeback: 128 b x 10 = 1280 floats
    __syncthreads();
    if (tid < 128) {
        #pragma unroll
        for (int c = 0; c < 10; ++c) sA[tid * 11 + c] = oc[c];
    }
    __syncthreads();
    const size_t obase = (size_t)blockIdx.x * 1280;
    for (int i = tid; i < 1280; i += 512) {
        const int bl = i / 10;
        outputs[obase + i] = sA[bl * 11 + (i - bl * 10)];
    }
}

extern "C" void kernel_launch(void* const* d_in, const int* in_sizes, int n_in,
                              void* d_out, int out_size, void* d_ws, size_t ws_size,
                              hipStream_t stream) {
    const float* w0   = (const float*)d_in[0];
    const float* w1   = (const float*)d_in[1];
    const float* w2   = (const float*)d_in[2];
    const float* w3   = (const float*)d_in[3];
    const float* Wlin = (const float*)d_in[4];
    const float* blin = (const float*)d_in[5];
    const float* Wq   = (const float*)d_in[6];
    const float* bq   = (const float*)d_in[7];
    const float* Wk   = (const float*)d_in[8];
    const float* bk   = (const float*)d_in[9];
    const float* Wv   = (const float*)d_in[10];
    const float* bv   = (const float*)d_in[11];
    const float* Wfin = (const float*)d_in[12];
    const float* bfin = (const float*)d_in[13];

    char* ws = (char*)d_ws;
    ushort* Wcomb16 = (ushort*)ws;                          // 256 KiB  [4][32][1024] f16
    float*  bcomb   = (float*)(ws + ((size_t)256 << 10));   // 512 B    [4][32]

    float* outputs = (float*)d_out;
    float* attn    = outputs + (size_t)B_ROWS * 10;

    k_prep<<<256, 128, 0, stream>>>(Wlin, blin, Wq, Wk, Wv, bq, bk, bv, Wcomb16, bcomb);
    k_all <<<256, 512, 0, stream>>>(w0, w1, w2, w3, Wcomb16, bcomb, Wfin, bfin, outputs, attn);
}

// Round 7
// 589.083 us; speedup vs baseline: 1.2213x; 1.2213x over previous
//
#include <hip/hip_runtime.h>
#include <stdint.h>

#define B_ROWS 32768
#define F_DIM  1024
#define H_DIM  512

typedef __attribute__((ext_vector_type(4))) float    floatx4;
typedef __attribute__((ext_vector_type(2))) __fp16   fp16x2;
typedef __attribute__((ext_vector_type(8))) _Float16 halfx8;

__device__ __forceinline__ void async_load16(const void* g, void* l) {
    __builtin_amdgcn_global_load_lds(
        (const __attribute__((address_space(1))) void*)g,
        (__attribute__((address_space(3))) void*)l, 16, 0, 0);
}

// Non-temporal 16B load: keeps the 512MB w stream out of L2 (R5: -36%).
__device__ __forceinline__ floatx4 nt_load4(const float* p) {
    return __builtin_nontemporal_load((const floatx4*)p);
}

// --------------------------------------------------------------------------
// Wcomb[k,d,f] = sum_h Wqkv[k,d,h] * Wlin[k,h,f]   (d: 0-9 q, 10-19 k, 20-29 v)
// bcomb[k,d]   = b[k,d] + sum_h Wqkv[k,d,h] * blin[k,h]   (unchanged)
// --------------------------------------------------------------------------
__global__ __launch_bounds__(128) void k_prep(
    const float* __restrict__ Wlin, const float* __restrict__ blin,
    const float* __restrict__ Wq, const float* __restrict__ Wk,
    const float* __restrict__ Wv, const float* __restrict__ bq,
    const float* __restrict__ bk, const float* __restrict__ bv,
    ushort* __restrict__ Wcomb16, float* __restrict__ bcomb)
{
    __shared__ float sw_[H_DIM];
    __shared__ float sbl[H_DIM];
    const int bx   = blockIdx.x;
    const int k    = bx >> 6;
    const int d    = (bx >> 1) & 31;
    const int half = bx & 1;
    const int t    = threadIdx.x;
    const int col  = half * 512 + t * 4;
    ushort4* outp = (ushort4*)(Wcomb16 + (((size_t)(k * 32 + d)) << 10) + col);

    if (d >= 30) {
        ushort4 z; z.x = z.y = z.z = z.w = 0;
        *outp = z;
        if (half == 0 && t == 0) bcomb[k * 32 + d] = 0.f;
        return;
    }

    const float* wrow; float bias;
    if (d < 10)      { wrow = Wq + (size_t)(k * 10 + d) * H_DIM;      bias = bq[k * 10 + d]; }
    else if (d < 20) { wrow = Wk + (size_t)(k * 10 + d - 10) * H_DIM; bias = bk[k * 10 + d - 10]; }
    else             { wrow = Wv + (size_t)(k * 10 + d - 20) * H_DIM; bias = bv[k * 10 + d - 20]; }

    const float* bl = blin + (size_t)k * H_DIM;
    for (int i = t; i < H_DIM; i += 128) { sw_[i] = wrow[i]; sbl[i] = bl[i]; }
    __syncthreads();

    const float* wl = Wlin + (((size_t)k * H_DIM) << 10) + col;

    floatx4 acc0 = {0.f,0.f,0.f,0.f}, acc1 = {0.f,0.f,0.f,0.f};
    float ba0 = 0.f, ba1 = 0.f;
    #pragma unroll 8
    for (int h = 0; h < H_DIM; h += 2) {
        const float s0 = sw_[h], s1 = sw_[h + 1];
        const floatx4 x0 = *(const floatx4*)(wl + ((size_t)h << 10));
        const floatx4 x1 = *(const floatx4*)(wl + ((size_t)(h + 1) << 10));
        acc0 += x0 * s0;
        acc1 += x1 * s1;
        ba0 += s0 * sbl[h];
        ba1 += s1 * sbl[h + 1];
    }
    const floatx4 acc = acc0 + acc1;
    union { _Float16 h[4]; ushort4 u; } o;
    o.h[0] = (_Float16)acc.x; o.h[1] = (_Float16)acc.y;
    o.h[2] = (_Float16)acc.z; o.h[3] = (_Float16)acc.w;
    *outp = o.u;
    if (half == 0 && t == 0) bcomb[k * 32 + d] = bias + ba0 + ba1;
}

// --------------------------------------------------------------------------
// FUSED qkv+attention. R7 = proven R5 per-head structure +
//  (a) 8-deep A prefetch: abuf[8][2], clean fully-unrolled 32-step loop
//      (all indices static after unroll -- no scratch, rule #20)
//  (b) reg-staged Bs(k+1) (T14): loaded right after head-k prologue,
//      ds_write at boundary under raw s_barrier + lgkmcnt(0) only
//      -> no vmcnt(0) drain after the initial stage; A-stream never drains.
// --------------------------------------------------------------------------
#define SM_BS    0                        // 64 KiB  ushort[32*1024]
#define SM_QKV   (64 * 1024)              // 61.9 KiB float[128*121]
#define SM_BC    (SM_QKV + 128 * 121 * 4) // 512 B   float[128]
#define SM_W     (SM_BC + 512)            // 1600 B  float[400]
#define SM_B     (SM_W + 1600)            // 160 B   float[40]
#define SM_TOTAL (SM_B + 160)             // 129,824 B

__global__ __launch_bounds__(512, 2) void k_all(
    const float* __restrict__ w0, const float* __restrict__ w1,
    const float* __restrict__ w2, const float* __restrict__ w3,
    const ushort* __restrict__ Wcomb16, const float* __restrict__ bcomb,
    const float* __restrict__ Wfin, const float* __restrict__ bfin,
    float* __restrict__ outputs, float* __restrict__ attn)
{
    __shared__ __align__(16) unsigned char smem[SM_TOTAL];
    ushort* Bs  = (ushort*)(smem + SM_BS);
    float*  QKV = (float*) (smem + SM_QKV);   // [128][121]
    float*  sbc = (float*) (smem + SM_BC);
    float*  sW  = (float*) (smem + SM_W);
    float*  sb  = (float*) (smem + SM_B);
    float*  sA  = (float*) (smem + SM_BS);    // overlay after heads: [128][101]

    const int tid     = threadIdx.x;
    const int rowBase = blockIdx.x * 128;

    if (tid < 128) sbc[tid] = bcomb[tid];
    if (tid < 400) sW[tid]  = Wfin[tid];
    if (tid < 40)  sb[tid]  = bfin[tid];

    const int wv = tid >> 6;          // 0..7
    const int ln = tid & 63;
    const int lr = ln & 15;
    const int lq = ln >> 4;
    const int sw = lr & 7;            // Bs read-side swizzle key

    // ---- initial Bs (head 0): async global->LDS, slot-swizzled source
    #pragma unroll
    for (int it = 0; it < 8; ++it) {
        const int s   = it * 512 + tid;
        const int row = s >> 7;
        const int g   = (s & 127) ^ (row & 7);
        async_load16(Wcomb16 + (((size_t)row) << 10) + g * 8,
                     (ushort*)Bs + (size_t)s * 8);
    }
    __syncthreads();                  // the ONLY vmcnt(0) drain in the kernel

    const size_t aoff = (size_t)(rowBase + wv * 16 + lr) * F_DIM + lq * 8;

    #pragma unroll 1
    for (int k = 0; k < 4; ++k) {
        const float* aP = ((k == 0) ? w0 : (k == 1) ? w1 : (k == 2) ? w2 : w3) + aoff;

        // ---- A prefetch prologue: 8 slots (16 nt-loads in flight)
        floatx4 abuf[8][2];
        #pragma unroll
        for (int s = 0; s < 8; ++s) {
            abuf[s][0] = nt_load4(aP + s * 32);
            abuf[s][1] = nt_load4(aP + s * 32 + 4);
        }

        // ---- stage Bs(k+1) into registers (L2-resident; returns under compute)
        uint4 breg[8];
        if (k < 3) {
            const ushort* Wn = Wcomb16 + (((size_t)((k + 1) * 32)) << 10);
            #pragma unroll
            for (int it = 0; it < 8; ++it) {
                const int s   = it * 512 + tid;
                const int row = s >> 7;
                const int g   = (s & 127) ^ (row & 7);
                breg[it] = *(const uint4*)(Wn + (((size_t)row) << 10) + g * 8);
            }
        }

        floatx4 acc0 = {0.f,0.f,0.f,0.f};
        floatx4 acc1 = {0.f,0.f,0.f,0.f};

        // ---- clean 32-step loop: fully unrolls, all indices static
        #pragma unroll
        for (int t = 0; t < 32; ++t) {
            const floatx4 b0 = abuf[t & 7][0];
            const floatx4 b1 = abuf[t & 7][1];
            union { fp16x2 h2[4]; halfx8 h8; } u;
            u.h2[0] = __builtin_amdgcn_cvt_pkrtz(b0.x, b0.y);
            u.h2[1] = __builtin_amdgcn_cvt_pkrtz(b0.z, b0.w);
            u.h2[2] = __builtin_amdgcn_cvt_pkrtz(b1.x, b1.y);
            u.h2[3] = __builtin_amdgcn_cvt_pkrtz(b1.z, b1.w);
            const int slot_ = ((t * 4 + lq) ^ sw) * 8;
            const halfx8 bf0 = *(const halfx8*)&Bs[(lr << 10) + slot_];
            const halfx8 bf1 = *(const halfx8*)&Bs[((16 + lr) << 10) + slot_];
            acc0 = __builtin_amdgcn_mfma_f32_16x16x32_f16(u.h8, bf0, acc0, 0, 0, 0);
            acc1 = __builtin_amdgcn_mfma_f32_16x16x32_f16(u.h8, bf1, acc1, 0, 0, 0);
            if (t + 8 < 32) {
                abuf[t & 7][0] = nt_load4(aP + (t + 8) * 32);
                abuf[t & 7][1] = nt_load4(aP + (t + 8) * 32 + 4);
            }
        }

        // ---- QKV writes for head k. C/D: col(d)=lane&15 (+16j), row=(lane>>4)*4+reg.
        const int r0 = wv * 16 + lq * 4;
        #pragma unroll
        for (int r = 0; r < 4; ++r)
            QKV[(r0 + r) * 121 + k * 30 + lr] = acc0[r] + sbc[k * 32 + lr];
        const int d1 = 16 + lr;
        if (d1 < ((k == 0) ? 30 : 20)) {   // v only needed for head 0
            #pragma unroll
            for (int r = 0; r < 4; ++r)
                QKV[(r0 + r) * 121 + k * 30 + d1] = acc1[r] + sbc[k * 32 + d1];
        }

        // ---- head boundary: swap Bs from registers; vmcnt untouched
        if (k < 3) {
            __builtin_amdgcn_s_barrier();          // all waves done reading Bs(k)
            #pragma unroll
            for (int it = 0; it < 8; ++it)
                *(uint4*)((ushort*)Bs + (size_t)(it * 512 + tid) * 8) = breg[it];
            asm volatile("s_waitcnt lgkmcnt(0)" ::: "memory");
            __builtin_amdgcn_sched_barrier(0);
            __builtin_amdgcn_s_barrier();          // Bs(k+1) visible to all
        }
    }
    __syncthreads();   // QKV complete; Bs dead from here (sA overlays it)

    // ---------------- attention + heads epilogue (threads 0-127, 1 b-row each)
    float oc[10];
    if (tid < 128) {
        const float* Q = &QKV[tid * 121];
        float q[4][10], kk[4][10], v0[10];
        #pragma unroll
        for (int k = 0; k < 4; ++k)
            #pragma unroll
            for (int e = 0; e < 10; ++e) {
                q[k][e]  = Q[k * 30 + e];
                kk[k][e] = Q[k * 30 + 10 + e];
            }
        #pragma unroll
        for (int m = 0; m < 10; ++m) v0[m] = Q[20 + m];   // v, head 0

        float out0[10];
        #pragma unroll
        for (int e = 0; e < 10; ++e) out0[e] = 0.f;
        float* sAr = &sA[tid * 101];
        const float inv = 0.31622776601683794f;  // 1/sqrt(10)

        #pragma unroll
        for (int m = 0; m < 10; ++m) {
            float col[10]; float mx = -1e30f;
            #pragma unroll
            for (int e = 0; e < 10; ++e) {
                col[e] = (q[0][e]*kk[0][m] + q[1][e]*kk[1][m]
                        + q[2][e]*kk[2][m] + q[3][e]*kk[3][m]) * inv;
                mx = fmaxf(mx, col[e]);
            }
            float s = 0.f;
            #pragma unroll
            for (int e = 0; e < 10; ++e) { col[e] = __expf(col[e] - mx); s += col[e]; }
            const float r = 1.f / s;
            #pragma unroll
            for (int e = 0; e < 10; ++e) {
                const float a = col[e] * r;
                sAr[e * 10 + m] = a;
                out0[e] += a * v0[m];
            }
        }

        #pragma unroll
        for (int c = 0; c < 10; ++c) oc[c] = 0.f;
        #pragma unroll
        for (int k = 0; k < 4; ++k) {
            float lg[10]; float mx = -1e30f;
            #pragma unroll
            for (int c = 0; c < 10; ++c) {
                float s = sb[k * 10 + c];
                #pragma unroll
                for (int e = 0; e < 10; ++e) s += out0[e] * sW[(k * 10 + c) * 10 + e];
                lg[c] = s; mx = fmaxf(mx, s);
            }
            float s = 0.f;
            #pragma unroll
            for (int c = 0; c < 10; ++c) { lg[c] = __expf(lg[c] - mx); s += lg[c]; }
            const float r = 0.25f / s;
            #pragma unroll
            for (int c = 0; c < 10; ++c) oc[c] += lg[c] * r;
        }
    }

    // ---- coalesced attn writeback: 128 b x 100 = 12800 floats
    __syncthreads();
    const size_t abase = (size_t)blockIdx.x * 12800;
    for (int i = tid; i < 12800; i += 512) {
        const int bl = i / 100;
        attn[abase + i] = sA[bl * 101 + (i - bl * 100)];
    }

    // ---- coalesced outputs writeback: 128 b x 10 = 1280 floats
    __syncthreads();
    if (tid < 128) {
        #pragma unroll
        for (int c = 0; c < 10; ++c) sA[tid * 11 + c] = oc[c];
    }
    __syncthreads();
    const size_t obase = (size_t)blockIdx.x * 1280;
    for (int i = tid; i < 1280; i += 512) {
        const int bl = i / 10;
        outputs[obase + i] = sA[bl * 11 + (i - bl * 10)];
    }
}

extern "C" void kernel_launch(void* const* d_in, const int* in_sizes, int n_in,
                              void* d_out, int out_size, void* d_ws, size_t ws_size,
                              hipStream_t stream) {
    const float* w0   = (const float*)d_in[0];
    const float* w1   = (const float*)d_in[1];
    const float* w2   = (const float*)d_in[2];
    const float* w3   = (const float*)d_in[3];
    const float* Wlin = (const float*)d_in[4];
    const float* blin = (const float*)d_in[5];
    const float* Wq   = (const float*)d_in[6];
    const float* bq   = (const float*)d_in[7];
    const float* Wk   = (const float*)d_in[8];
    const float* bk   = (const float*)d_in[9];
    const float* Wv   = (const float*)d_in[10];
    const float* bv   = (const float*)d_in[11];
    const float* Wfin = (const float*)d_in[12];
    const float* bfin = (const float*)d_in[13];

    char* ws = (char*)d_ws;
    ushort* Wcomb16 = (ushort*)ws;                          // 256 KiB  [4][32][1024] f16
    float*  bcomb   = (float*)(ws + ((size_t)256 << 10));   // 512 B    [4][32]

    float* outputs = (float*)d_out;
    float* attn    = outputs + (size_t)B_ROWS * 10;

    k_prep<<<256, 128, 0, stream>>>(Wlin, blin, Wq, Wk, Wv, bq, bk, bv, Wcomb16, bcomb);
    k_all <<<256, 512, 0, stream>>>(w0, w1, w2, w3, Wcomb16, bcomb, Wfin, bfin, outputs, attn);
}

// Round 8
// 550.190 us; speedup vs baseline: 1.3076x; 1.0707x over previous
//
#include <hip/hip_runtime.h>
#include <stdint.h>

#define B_ROWS 32768
#define F_DIM  1024
#define H_DIM  512

typedef __attribute__((ext_vector_type(4))) float    floatx4;
typedef __attribute__((ext_vector_type(2))) __fp16   fp16x2;
typedef __attribute__((ext_vector_type(8))) _Float16 halfx8;

__device__ __forceinline__ void async_load16(const void* g, void* l) {
    __builtin_amdgcn_global_load_lds(
        (const __attribute__((address_space(1))) void*)g,
        (__attribute__((address_space(3))) void*)l, 16, 0, 0);
}

// Non-temporal 16B load: keeps the 512MB w stream out of L2 (R5: -36%).
__device__ __forceinline__ floatx4 nt_load4(const float* p) {
    return __builtin_nontemporal_load((const floatx4*)p);
}

// --------------------------------------------------------------------------
// Wcomb[k,d,f] = sum_h Wqkv[k,d,h] * Wlin[k,h,f]   (d: 0-9 q, 10-19 k, 20-29 v)
// bcomb[k,d]   = b[k,d] + sum_h Wqkv[k,d,h] * blin[k,h]   (unchanged)
// --------------------------------------------------------------------------
__global__ __launch_bounds__(128) void k_prep(
    const float* __restrict__ Wlin, const float* __restrict__ blin,
    const float* __restrict__ Wq, const float* __restrict__ Wk,
    const float* __restrict__ Wv, const float* __restrict__ bq,
    const float* __restrict__ bk, const float* __restrict__ bv,
    ushort* __restrict__ Wcomb16, float* __restrict__ bcomb)
{
    __shared__ float sw_[H_DIM];
    __shared__ float sbl[H_DIM];
    const int bx   = blockIdx.x;
    const int k    = bx >> 6;
    const int d    = (bx >> 1) & 31;
    const int half = bx & 1;
    const int t    = threadIdx.x;
    const int col  = half * 512 + t * 4;
    ushort4* outp = (ushort4*)(Wcomb16 + (((size_t)(k * 32 + d)) << 10) + col);

    if (d >= 30) {
        ushort4 z; z.x = z.y = z.z = z.w = 0;
        *outp = z;
        if (half == 0 && t == 0) bcomb[k * 32 + d] = 0.f;
        return;
    }

    const float* wrow; float bias;
    if (d < 10)      { wrow = Wq + (size_t)(k * 10 + d) * H_DIM;      bias = bq[k * 10 + d]; }
    else if (d < 20) { wrow = Wk + (size_t)(k * 10 + d - 10) * H_DIM; bias = bk[k * 10 + d - 10]; }
    else             { wrow = Wv + (size_t)(k * 10 + d - 20) * H_DIM; bias = bv[k * 10 + d - 20]; }

    const float* bl = blin + (size_t)k * H_DIM;
    for (int i = t; i < H_DIM; i += 128) { sw_[i] = wrow[i]; sbl[i] = bl[i]; }
    __syncthreads();

    const float* wl = Wlin + (((size_t)k * H_DIM) << 10) + col;

    floatx4 acc0 = {0.f,0.f,0.f,0.f}, acc1 = {0.f,0.f,0.f,0.f};
    float ba0 = 0.f, ba1 = 0.f;
    #pragma unroll 8
    for (int h = 0; h < H_DIM; h += 2) {
        const float s0 = sw_[h], s1 = sw_[h + 1];
        const floatx4 x0 = *(const floatx4*)(wl + ((size_t)h << 10));
        const floatx4 x1 = *(const floatx4*)(wl + ((size_t)(h + 1) << 10));
        acc0 += x0 * s0;
        acc1 += x1 * s1;
        ba0 += s0 * sbl[h];
        ba1 += s1 * sbl[h + 1];
    }
    const floatx4 acc = acc0 + acc1;
    union { _Float16 h[4]; ushort4 u; } o;
    o.h[0] = (_Float16)acc.x; o.h[1] = (_Float16)acc.y;
    o.h[2] = (_Float16)acc.z; o.h[3] = (_Float16)acc.w;
    *outp = o.u;
    if (half == 0 && t == 0) bcomb[k * 32 + d] = bias + ba0 + ba1;
}

// --------------------------------------------------------------------------
// FUSED qkv+attention. R8 = R5 structure restored (proven 124us), with:
//  (a) depth-4 A prefetch: abuf[4][2], clean fully-unrolled 32-step loop
//      (same VGPR count as R5's ping-pong; smoother issue)
//  (b) A-prologue hoisted ABOVE the Bs staging at each head boundary:
//      the __syncthreads vmcnt-drain covers both, so compute starts with
//      A-data resident (no post-barrier latency bubble).
// NO reg-staged Bs (spilled in R6/R7: WRITE_SIZE is the tripwire).
// --------------------------------------------------------------------------
#define SM_BS    0                        // 64 KiB  ushort[32*1024]
#define SM_QKV   (64 * 1024)              // 61.9 KiB float[128*121]
#define SM_BC    (SM_QKV + 128 * 121 * 4) // 512 B   float[128]
#define SM_W     (SM_BC + 512)            // 1600 B  float[400]
#define SM_B     (SM_W + 1600)            // 160 B   float[40]
#define SM_TOTAL (SM_B + 160)             // 129,824 B

__global__ __launch_bounds__(512) void k_all(
    const float* __restrict__ w0, const float* __restrict__ w1,
    const float* __restrict__ w2, const float* __restrict__ w3,
    const ushort* __restrict__ Wcomb16, const float* __restrict__ bcomb,
    const float* __restrict__ Wfin, const float* __restrict__ bfin,
    float* __restrict__ outputs, float* __restrict__ attn)
{
    __shared__ __align__(16) unsigned char smem[SM_TOTAL];
    ushort* Bs  = (ushort*)(smem + SM_BS);
    float*  QKV = (float*) (smem + SM_QKV);   // [128][121]
    float*  sbc = (float*) (smem + SM_BC);
    float*  sW  = (float*) (smem + SM_W);
    float*  sb  = (float*) (smem + SM_B);
    float*  sA  = (float*) (smem + SM_BS);    // overlay after heads: [128][101]

    const int tid     = threadIdx.x;
    const int rowBase = blockIdx.x * 128;

    if (tid < 128) sbc[tid] = bcomb[tid];
    if (tid < 400) sW[tid]  = Wfin[tid];
    if (tid < 40)  sb[tid]  = bfin[tid];

    const int wv = tid >> 6;          // 0..7
    const int ln = tid & 63;
    const int lr = ln & 15;
    const int lq = ln >> 4;
    const int sw = lr & 7;            // Bs read-side swizzle key

    const size_t aoff = (size_t)(rowBase + wv * 16 + lr) * F_DIM + lq * 8;

    #pragma unroll 1
    for (int k = 0; k < 4; ++k) {
        const float* aP = ((k == 0) ? w0 : (k == 1) ? w1 : (k == 2) ? w2 : w3) + aoff;

        // ---- (b) A-prologue first: 8 nt-loads in flight before the drain
        floatx4 abuf[4][2];
        #pragma unroll
        for (int s = 0; s < 4; ++s) {
            abuf[s][0] = nt_load4(aP + s * 32);
            abuf[s][1] = nt_load4(aP + s * 32 + 4);
        }

        if (k > 0) __builtin_amdgcn_s_barrier();  // all waves done reading Bs(k-1)

        // ---- Bs(k) staging: async global->LDS, slot-swizzled source
        #pragma unroll
        for (int it = 0; it < 8; ++it) {
            const int s   = it * 512 + tid;
            const int row = s >> 7;
            const int g   = (s & 127) ^ (row & 7);
            async_load16(Wcomb16 + (((size_t)(k * 32 + row)) << 10) + g * 8,
                         (ushort*)Bs + (size_t)s * 8);
        }
        __syncthreads();              // drains vmcnt: Bs AND abuf ready

        floatx4 acc0 = {0.f,0.f,0.f,0.f};
        floatx4 acc1 = {0.f,0.f,0.f,0.f};

        // ---- clean 32-step loop: fully unrolls, all indices static
        #pragma unroll
        for (int t = 0; t < 32; ++t) {
            const floatx4 b0 = abuf[t & 3][0];
            const floatx4 b1 = abuf[t & 3][1];
            union { fp16x2 h2[4]; halfx8 h8; } u;
            u.h2[0] = __builtin_amdgcn_cvt_pkrtz(b0.x, b0.y);
            u.h2[1] = __builtin_amdgcn_cvt_pkrtz(b0.z, b0.w);
            u.h2[2] = __builtin_amdgcn_cvt_pkrtz(b1.x, b1.y);
            u.h2[3] = __builtin_amdgcn_cvt_pkrtz(b1.z, b1.w);
            const int slot_ = ((t * 4 + lq) ^ sw) * 8;
            const halfx8 bf0 = *(const halfx8*)&Bs[(lr << 10) + slot_];
            const halfx8 bf1 = *(const halfx8*)&Bs[((16 + lr) << 10) + slot_];
            acc0 = __builtin_amdgcn_mfma_f32_16x16x32_f16(u.h8, bf0, acc0, 0, 0, 0);
            acc1 = __builtin_amdgcn_mfma_f32_16x16x32_f16(u.h8, bf1, acc1, 0, 0, 0);
            if (t + 4 < 32) {
                abuf[t & 3][0] = nt_load4(aP + (t + 4) * 32);
                abuf[t & 3][1] = nt_load4(aP + (t + 4) * 32 + 4);
            }
        }

        // ---- QKV writes for head k. C/D: col(d)=lane&15 (+16j), row=(lane>>4)*4+reg.
        const int r0 = wv * 16 + lq * 4;
        #pragma unroll
        for (int r = 0; r < 4; ++r)
            QKV[(r0 + r) * 121 + k * 30 + lr] = acc0[r] + sbc[k * 32 + lr];
        const int d1 = 16 + lr;
        if (d1 < ((k == 0) ? 30 : 20)) {   // v only needed for head 0
            #pragma unroll
            for (int r = 0; r < 4; ++r)
                QKV[(r0 + r) * 121 + k * 30 + d1] = acc1[r] + sbc[k * 32 + d1];
        }
    }
    __syncthreads();   // QKV complete; Bs dead from here (sA overlays it)

    // ---------------- attention + heads epilogue (threads 0-127, 1 b-row each)
    float oc[10];
    if (tid < 128) {
        const float* Q = &QKV[tid * 121];
        float q[4][10], kk[4][10], v0[10];
        #pragma unroll
        for (int k = 0; k < 4; ++k)
            #pragma unroll
            for (int e = 0; e < 10; ++e) {
                q[k][e]  = Q[k * 30 + e];
                kk[k][e] = Q[k * 30 + 10 + e];
            }
        #pragma unroll
        for (int m = 0; m < 10; ++m) v0[m] = Q[20 + m];   // v, head 0

        float out0[10];
        #pragma unroll
        for (int e = 0; e < 10; ++e) out0[e] = 0.f;
        float* sAr = &sA[tid * 101];
        const float inv = 0.31622776601683794f;  // 1/sqrt(10)

        #pragma unroll
        for (int m = 0; m < 10; ++m) {
            float col[10]; float mx = -1e30f;
            #pragma unroll
            for (int e = 0; e < 10; ++e) {
                col[e] = (q[0][e]*kk[0][m] + q[1][e]*kk[1][m]
                        + q[2][e]*kk[2][m] + q[3][e]*kk[3][m]) * inv;
                mx = fmaxf(mx, col[e]);
            }
            float s = 0.f;
            #pragma unroll
            for (int e = 0; e < 10; ++e) { col[e] = __expf(col[e] - mx); s += col[e]; }
            const float r = 1.f / s;
            #pragma unroll
            for (int e = 0; e < 10; ++e) {
                const float a = col[e] * r;
                sAr[e * 10 + m] = a;
                out0[e] += a * v0[m];
            }
        }

        #pragma unroll
        for (int c = 0; c < 10; ++c) oc[c] = 0.f;
        #pragma unroll
        for (int k = 0; k < 4; ++k) {
            float lg[10]; float mx = -1e30f;
            #pragma unroll
            for (int c = 0; c < 10; ++c) {
                float s = sb[k * 10 + c];
                #pragma unroll
                for (int e = 0; e < 10; ++e) s += out0[e] * sW[(k * 10 + c) * 10 + e];
                lg[c] = s; mx = fmaxf(mx, s);
            }
            float s = 0.f;
            #pragma unroll
            for (int c = 0; c < 10; ++c) { lg[c] = __expf(lg[c] - mx); s += lg[c]; }
            const float r = 0.25f / s;
            #pragma unroll
            for (int c = 0; c < 10; ++c) oc[c] += lg[c] * r;
        }
    }

    // ---- coalesced attn writeback: 128 b x 100 = 12800 floats
    __syncthreads();
    const size_t abase = (size_t)blockIdx.x * 12800;
    for (int i = tid; i < 12800; i += 512) {
        const int bl = i / 100;
        attn[abase + i] = sA[bl * 101 + (i - bl * 100)];
    }

    // ---- coalesced outputs writeback: 128 b x 10 = 1280 floats
    __syncthreads();
    if (tid < 128) {
        #pragma unroll
        for (int c = 0; c < 10; ++c) sA[tid * 11 + c] = oc[c];
    }
    __syncthreads();
    const size_t obase = (size_t)blockIdx.x * 1280;
    for (int i = tid; i < 1280; i += 512) {
        const int bl = i / 10;
        outputs[obase + i] = sA[bl * 11 + (i - bl * 10)];
    }
}

extern "C" void kernel_launch(void* const* d_in, const int* in_sizes, int n_in,
                              void* d_out, int out_size, void* d_ws, size_t ws_size,
                              hipStream_t stream) {
    const float* w0   = (const float*)d_in[0];
    const float* w1   = (const float*)d_in[1];
    const float* w2   = (const float*)d_in[2];
    const float* w3   = (const float*)d_in[3];
    const float* Wlin = (const float*)d_in[4];
    const float* blin = (const float*)d_in[5];
    const float* Wq   = (const float*)d_in[6];
    const float* bq   = (const float*)d_in[7];
    const float* Wk   = (const float*)d_in[8];
    const float* bk   = (const float*)d_in[9];
    const float* Wv   = (const float*)d_in[10];
    const float* bv   = (const float*)d_in[11];
    const float* Wfin = (const float*)d_in[12];
    const float* bfin = (const float*)d_in[13];

    char* ws = (char*)d_ws;
    ushort* Wcomb16 = (ushort*)ws;                          // 256 KiB  [4][32][1024] f16
    float*  bcomb   = (float*)(ws + ((size_t)256 << 10));   // 512 B    [4][32]

    float* outputs = (float*)d_out;
    float* attn    = outputs + (size_t)B_ROWS * 10;

    k_prep<<<256, 128, 0, stream>>>(Wlin, blin, Wq, Wk, Wv, bq, bk, bv, Wcomb16, bcomb);
    k_all <<<256, 512, 0, stream>>>(w0, w1, w2, w3, Wcomb16, bcomb, Wfin, bfin, outputs, attn);
}